// Round 8
// baseline (582.455 us; speedup 1.0000x reference)
//
#include <hip/hip_runtime.h>
#include <math.h>

#define G 1200
#define NIN 10
#define NHE 300
#define NINC 4800
#define ALPHA 0.005f
#define BETA 5e-5f
#define BN_EPS 1e-5f
#define NBLK 1200
#define NSTR 16
#define STRI 32  // ints per stripe line (128 B)

struct Params {
    const float *x, *edge1, *edge2, *W1, *b1, *iw, *ib;
    const float *e1w, *e1b, *e2w, *e2b;
    const float *n1w, *n1b, *n2w, *n2b;
    const float *m1w, *m1b, *m2w, *m2b, *m3w, *m3b;
    const float *hgw, *hgb;
    const int *hn, *he;
    float4 *xfeat2, *upd2;
    float *a2, *c2, *efeat;
    int *eh;
    int *bar0, *bar1, *flag0, *flag1;
    float4 *out;
};

__device__ __forceinline__ float eluf(float x) { return x > 0.f ? x : __expf(x) - 1.f; }
__device__ __forceinline__ float sigf(float x) { return 1.f / (1.f + __expf(-x)); }
__device__ __forceinline__ float wred(float v) {
#pragma unroll
    for (int o = 32; o > 0; o >>= 1) v += __shfl_down(v, o, 64);
    return v;
}
__device__ __forceinline__ float maskf(float e, float coef) { return (e == 0.f) ? coef : e; }

// Device-wide barrier: striped arrivals + single master aggregates + one release flag.
// Pollers back off with s_sleep (~0.1us) -> no fabric storm (r5 lesson). Bounded spin:
// worst case exits in ~0.4s -> absmax failure, never a harness timeout.
__device__ void gbar(int* stripes, int* flag, int blk, int tid) {
    __syncthreads();
    if (tid == 0) {
        __threadfence();
        atomicAdd(&stripes[(blk & (NSTR - 1)) * STRI], 1);
        if (blk == 0) {
            for (int it = 0; it < (1 << 22); ++it) {
                int s = 0;
#pragma unroll
                for (int k = 0; k < NSTR; ++k)
                    s += __hip_atomic_load(&stripes[k * STRI], __ATOMIC_RELAXED,
                                           __HIP_MEMORY_SCOPE_AGENT);
                if (s >= NBLK) break;
                __builtin_amdgcn_s_sleep(4);
            }
            __hip_atomic_store(flag, 1, __ATOMIC_RELEASE, __HIP_MEMORY_SCOPE_AGENT);
        } else {
            for (int it = 0; it < (1 << 22); ++it) {
                if (__hip_atomic_load(flag, __ATOMIC_ACQUIRE, __HIP_MEMORY_SCOPE_AGENT)) break;
                __builtin_amdgcn_s_sleep(4);
            }
        }
        __threadfence();
    }
    __syncthreads();
}

// Phase 1 (blocks 0..599): fused infer + round1, 2 genes per block (i, i+600).
__device__ void phase1(const Params& p, int blk, int tid) {
    const int lane = tid & 63;
    const int w = tid >> 6;  // batch
    const int i0 = blk, i1 = blk + 600;

    float hi0[4], hi1[4];
    {
        const float* xp0 = p.x + ((size_t)w * G + i0) * NIN;
        const float* xp1 = p.x + ((size_t)w * G + i1) * NIN;
#pragma unroll
        for (int f = 0; f < 4; ++f) {
            float s0 = p.ib[f], s1 = p.ib[f];
#pragma unroll
            for (int k = 0; k < NIN; ++k) {
                s0 += p.iw[f * NIN + k] * xp0[k];
                s1 += p.iw[f * NIN + k] * xp1[k];
            }
            hi0[f] = eluf(s0);
            hi1[f] = eluf(s1);
        }
    }
    const float cb0 = p.e1w[4] * hi0[0] + p.e1w[5] * hi0[1] + p.e1w[6] * hi0[2] + p.e1w[7] * hi0[3] + p.e1b[0];
    const float cb1 = p.e1w[4] * hi1[0] + p.e1w[5] * hi1[1] + p.e1w[6] * hi1[2] + p.e1w[7] * hi1[3] + p.e1b[0];

    const float4* r0 = (const float4*)(p.edge1 + (size_t)i0 * G);
    const float4* r1 = (const float4*)(p.edge1 + (size_t)i1 * G);

    float acc[10];
#pragma unroll
    for (int k = 0; k < 10; ++k) acc[k] = 0.f;

    for (int m = lane; m < 300; m += 64) {
        float e0a[4], e1a[4];
        *(float4*)e0a = r0[m];
        *(float4*)e1a = r1[m];
        float xf[40];
        const float* xp = p.x + ((size_t)w * G + 4 * m) * NIN;
#pragma unroll
        for (int q = 0; q < 10; ++q) *(float4*)&xf[4 * q] = ((const float4*)xp)[q];
#pragma unroll
        for (int s = 0; s < 4; ++s) {
            float h[4];
#pragma unroll
            for (int f = 0; f < 4; ++f) {
                float sv = p.ib[f];
#pragma unroll
                for (int k = 0; k < NIN; ++k) sv += p.iw[f * NIN + k] * xf[10 * s + k];
                h[f] = eluf(sv);
            }
            float aj = p.e1w[0] * h[0] + p.e1w[1] * h[1] + p.e1w[2] * h[2] + p.e1w[3] * h[3];
            float sg0 = sigf(aj + cb0) * maskf(e0a[s], ALPHA);
            float sg1 = sigf(aj + cb1) * maskf(e1a[s], ALPHA);
            acc[0] += sg0 * h[0]; acc[1] += sg0 * h[1]; acc[2] += sg0 * h[2];
            acc[3] += sg0 * h[3]; acc[4] += sg0;
            acc[5] += sg1 * h[0]; acc[6] += sg1 * h[1]; acc[7] += sg1 * h[2];
            acc[8] += sg1 * h[3]; acc[9] += sg1;
        }
    }
#pragma unroll
    for (int k = 0; k < 10; ++k) acc[k] = wred(acc[k]);

    __shared__ float t[2][4][5];
    __shared__ float him[2][4][4];
    __shared__ float hvs[2][4][4];
    __shared__ float stats[2][2];

    if (lane == 0) {
#pragma unroll
        for (int k = 0; k < 5; ++k) { t[0][w][k] = acc[k]; t[1][w][k] = acc[5 + k]; }
#pragma unroll
        for (int f = 0; f < 4; ++f) { him[0][w][f] = hi0[f]; him[1][w][f] = hi1[f]; }
    }
    __syncthreads();

    if (tid < 8) {
        const int b = tid & 3, g = tid >> 2;
        const int i = (g == 0) ? i0 : i1;
        float xi[4] = {him[g][b][0], him[g][b][1], him[g][b][2], him[g][b][3]};
        float ssum = t[g][b][4];
        float r8[8];
#pragma unroll
        for (int k = 0; k < 4; ++k) { r8[k] = t[g][b][k]; r8[4 + k] = xi[k] * ssum; }
        float r[4];
#pragma unroll
        for (int f = 0; f < 4; ++f) {
            float sv = p.n1b[f];
#pragma unroll
            for (int k = 0; k < 8; ++k) sv += p.n1w[f * 8 + k] * r8[k];
            r[f] = eluf(sv);
        }
        const float w1d = p.W1[(size_t)i * G + i], b1i = p.b1[i];
#pragma unroll
        for (int f = 0; f < 4; ++f) {
            float sv = p.m1b[f];
#pragma unroll
            for (int k = 0; k < 4; ++k) sv += p.m1w[f * 8 + k] * r[k] + p.m1w[f * 8 + 4 + k] * xi[k];
            hvs[g][b][f] = eluf(eluf(sv) * w1d + b1i);
        }
    }
    __syncthreads();

    if (tid < 2) {  // BN per gene over (batch, feat) = 16 values
        const int g = tid;
        float mean = 0.f;
#pragma unroll
        for (int bb = 0; bb < 4; ++bb)
#pragma unroll
            for (int f = 0; f < 4; ++f) mean += hvs[g][bb][f];
        mean *= (1.f / 16.f);
        float var = 0.f;
#pragma unroll
        for (int bb = 0; bb < 4; ++bb)
#pragma unroll
            for (int f = 0; f < 4; ++f) { float d = hvs[g][bb][f] - mean; var += d * d; }
        var *= (1.f / 16.f);
        stats[g][0] = mean;
        stats[g][1] = rsqrtf(var + BN_EPS);
    }
    __syncthreads();

    if (tid < 8) {
        const int b = tid & 3, g = tid >> 2;
        const int i = (g == 0) ? i0 : i1;
        const float mean = stats[g][0], sc = stats[g][1];
        float hv[4];
#pragma unroll
        for (int f = 0; f < 4; ++f) hv[f] = (hvs[g][b][f] - mean) * sc;
        p.xfeat2[b * G + i] = make_float4(hv[0], hv[1], hv[2], hv[3]);
        p.a2[b * G + i] = p.e2w[0] * hv[0] + p.e2w[1] * hv[1] + p.e2w[2] * hv[2] + p.e2w[3] * hv[3];
        p.c2[b * G + i] = p.e2w[4] * hv[0] + p.e2w[5] * hv[1] + p.e2w[6] * hv[2] + p.e2w[7] * hv[3] + p.e2b[0];
    }
}

// Phase 2 (all 1200 blocks, gene i = blk): round2 -> upd2; scatter bs into global efeat/eh.
__device__ void phase2(const Params& p, int blk, int tid) {
    const int i = blk;
    const int lane = tid & 63;
    const int w = tid >> 6;

    const float cb = p.c2[w * G + i];
    const float4* erow4 = (const float4*)(p.edge2 + (size_t)i * G);
    const float4* a4 = (const float4*)(p.a2 + (size_t)w * G);

    float acc0 = 0.f, acc1 = 0.f, acc2 = 0.f, acc3 = 0.f, acc4 = 0.f;
    for (int m = lane; m < 300; m += 64) {
        float ea[4], aa[4];
        *(float4*)ea = erow4[m];
        *(float4*)aa = a4[m];
#pragma unroll
        for (int s = 0; s < 4; ++s) {
            float4 xv = p.xfeat2[w * G + 4 * m + s];
            float sg = sigf(aa[s] + cb) * maskf(ea[s], BETA);
            acc0 += sg * xv.x;
            acc1 += sg * xv.y;
            acc2 += sg * xv.z;
            acc3 += sg * xv.w;
            acc4 += sg;
        }
    }
    acc0 = wred(acc0); acc1 = wred(acc1); acc2 = wred(acc2); acc3 = wred(acc3); acc4 = wred(acc4);

    __shared__ float t[4][5];
    __shared__ float hvs[4][4];
    __shared__ float stats[2];
    __shared__ float bsf[4];
    if (lane == 0) { t[w][0] = acc0; t[w][1] = acc1; t[w][2] = acc2; t[w][3] = acc3; t[w][4] = acc4; }
    __syncthreads();

    if (tid < 4) {
        const int b = tid;
        float4 xi4 = p.xfeat2[b * G + i];
        float xi[4] = {xi4.x, xi4.y, xi4.z, xi4.w};
        float ssum = t[b][4];
        float r8[8];
#pragma unroll
        for (int k = 0; k < 4; ++k) { r8[k] = t[b][k]; r8[4 + k] = xi[k] * ssum; }
        float r[4];
#pragma unroll
        for (int f = 0; f < 4; ++f) {
            float sv = p.n2b[f];
#pragma unroll
            for (int k = 0; k < 8; ++k) sv += p.n2w[f * 8 + k] * r8[k];
            r[f] = eluf(sv);
        }
#pragma unroll
        for (int f = 0; f < 4; ++f) {
            float sv = p.m2b[f];
#pragma unroll
            for (int k = 0; k < 4; ++k) sv += p.m2w[f * 8 + k] * r[k] + p.m2w[f * 8 + 4 + k] * xi[k];
            hvs[b][f] = eluf(sv);
        }
    }
    __syncthreads();

    if (tid == 0) {
        float mean = 0.f;
#pragma unroll
        for (int bb = 0; bb < 4; ++bb)
#pragma unroll
            for (int f = 0; f < 4; ++f) mean += hvs[bb][f];
        mean *= (1.f / 16.f);
        float var = 0.f;
#pragma unroll
        for (int bb = 0; bb < 4; ++bb)
#pragma unroll
            for (int f = 0; f < 4; ++f) { float d = hvs[bb][f] - mean; var += d * d; }
        var *= (1.f / 16.f);
        stats[0] = mean;
        stats[1] = rsqrtf(var + BN_EPS);
    }
    __syncthreads();

    if (tid < 4) {
        const int b = tid;
        const float mean = stats[0], sc = stats[1];
        float hv[4];
#pragma unroll
        for (int f = 0; f < 4; ++f) hv[f] = (hvs[b][f] - mean) * sc;
        p.upd2[b * G + i] = make_float4(hv[0], hv[1], hv[2], hv[3]);
        hvs[b][0] = hv[0]; hvs[b][1] = hv[1]; hvs[b][2] = hv[2]; hvs[b][3] = hv[3];
    }
    __syncthreads();

    if (tid < 4) {
        const int f = tid;
        float sv = 0.f;
#pragma unroll
        for (int bb = 0; bb < 4; ++bb)
#pragma unroll
            for (int k = 0; k < 4; ++k) sv += p.hgw[f * 4 + k] * hvs[bb][k];
        bsf[f] = sv;
    }
    __syncthreads();

    const float v0 = bsf[0], v1 = bsf[1], v2 = bsf[2], v3 = bsf[3];
    for (int cI = tid; cI < NINC; cI += 256) {
        if (p.hn[cI] == i) {
            int e = p.he[cI];
            atomicAdd(&p.eh[e], 1);
            atomicAdd(&p.efeat[e * 4 + 0], v0);
            atomicAdd(&p.efeat[e * 4 + 1], v1);
            atomicAdd(&p.efeat[e * 4 + 2], v2);
            atomicAdd(&p.efeat[e * 4 + 3], v3);
        }
    }
}

// Phase 3 (all 1200 blocks, gene i = blk): gather hx[i] + final MLP (x4 batches).
__device__ void phase3(const Params& p, int blk, int tid) {
    const int i = blk;
    const int lane = tid & 63;
    const int w = tid >> 6;

    float a0 = 0.f, a1 = 0.f, a2v = 0.f, a3 = 0.f, cf = 0.f;
    for (int cI = tid; cI < NINC; cI += 256) {
        if (p.hn[cI] == i) {
            int e = p.he[cI];
            float binv = 0.25f / (float)p.eh[e];  // bdeg = BSZ * hist(edges)
            a0 += p.efeat[e * 4 + 0] * binv;
            a1 += p.efeat[e * 4 + 1] * binv;
            a2v += p.efeat[e * 4 + 2] * binv;
            a3 += p.efeat[e * 4 + 3] * binv;
            cf += 1.f;
        }
    }
    a0 = wred(a0); a1 = wred(a1); a2v = wred(a2v); a3 = wred(a3); cf = wred(cf);
    __shared__ float red[4][5];
    if (lane == 0) { red[w][0] = a0; red[w][1] = a1; red[w][2] = a2v; red[w][3] = a3; red[w][4] = cf; }
    __syncthreads();

    if (tid < 4) {
        const int b = tid;
        float dg = red[0][4] + red[1][4] + red[2][4] + red[3][4];
        float dinv = dg > 0.f ? 1.f / dg : 0.f;
        float hxp[4];
#pragma unroll
        for (int f = 0; f < 4; ++f) {
            float hx = (red[0][f] + red[1][f] + red[2][f] + red[3][f]) * dinv;
            hxp[f] = eluf(hx + p.hgb[f]);
        }
        float4 u4 = p.upd2[b * G + i];
        float u[4] = {u4.x, u4.y, u4.z, u4.w};
        float o4[4];
#pragma unroll
        for (int f = 0; f < 4; ++f) {
            float sv = p.m3b[f];
#pragma unroll
            for (int k = 0; k < 4; ++k)
                sv += p.m3w[f * 8 + k] * u[k] + p.m3w[f * 8 + 4 + k] * hxp[k];
            o4[f] = eluf(sv);
        }
        p.out[b * G + i] = make_float4(o4[0], o4[1], o4[2], o4[3]);
    }
}

__global__ __launch_bounds__(256, 8)  // VGPR<=64 -> 2048-block capacity >> 1200: co-residency certain
void mega_kernel(Params p) {
    const int blk = blockIdx.x, tid = threadIdx.x;
    if (blk < 600) phase1(p, blk, tid);
    gbar(p.bar0, p.flag0, blk, tid);
    phase2(p, blk, tid);
    gbar(p.bar1, p.flag1, blk, tid);
    phase3(p, blk, tid);
}

extern "C" void kernel_launch(void* const* d_in, const int* in_sizes, int n_in,
                              void* d_out, int out_size, void* d_ws, size_t ws_size,
                              hipStream_t stream) {
    Params p;
    p.x     = (const float*)d_in[0];
    p.edge1 = (const float*)d_in[1];
    p.edge2 = (const float*)d_in[2];
    p.W1    = (const float*)d_in[3];
    p.b1    = (const float*)d_in[4];
    p.iw    = (const float*)d_in[5];
    p.ib    = (const float*)d_in[6];
    p.e1w   = (const float*)d_in[7];
    p.e1b   = (const float*)d_in[8];
    p.e2w   = (const float*)d_in[9];
    p.e2b   = (const float*)d_in[10];
    p.n1w   = (const float*)d_in[11];
    p.n1b   = (const float*)d_in[12];
    p.n2w   = (const float*)d_in[13];
    p.n2b   = (const float*)d_in[14];
    p.m1w   = (const float*)d_in[15];
    p.m1b   = (const float*)d_in[16];
    p.m2w   = (const float*)d_in[17];
    p.m2b   = (const float*)d_in[18];
    p.m3w   = (const float*)d_in[19];
    p.m3b   = (const float*)d_in[20];
    p.hgw   = (const float*)d_in[21];
    p.hgb   = (const float*)d_in[22];
    p.hn    = (const int*)d_in[23];
    p.he    = (const int*)d_in[24];

    char* ws = (char*)d_ws;
    p.xfeat2 = (float4*)(ws + 0);        // 76800
    p.upd2   = (float4*)(ws + 76800);    // 76800
    p.a2     = (float*)(ws + 153600);    // 19200
    p.c2     = (float*)(ws + 172800);    // 19200
    // ---- memset-covered region: efeat .. flags ----
    p.efeat  = (float*)(ws + 192000);    // 1200 f32 = 4800
    p.eh     = (int*)(ws + 196800);      // 300 i32  = 1200
    p.bar0   = (int*)(ws + 198016);      // 16*32 i32 = 2048 (128B-aligned)
    p.bar1   = (int*)(ws + 200064);      // 2048
    p.flag0  = (int*)(ws + 202112);      // own 128B line
    p.flag1  = (int*)(ws + 202240);      // own 128B line
    p.out    = (float4*)d_out;

    hipMemsetAsync(ws + 192000, 0, 202368 - 192000, stream);
    mega_kernel<<<NBLK, 256, 0, stream>>>(p);
}

// Round 9
// 151.866 us; speedup vs baseline: 3.8353x; 3.8353x over previous
//
#include <hip/hip_runtime.h>
#include <math.h>

#define G 1200
#define NIN 10
#define NHE 300
#define NINC 4800
#define ALPHA 0.005f
#define BETA 5e-5f
#define BN_EPS 1e-5f
#define NBLK 1200
#define NSTR 64   // arrival stripes (128B apart)
#define NMIR 8    // release mirror flags (128B apart)
#define STRI 32   // ints per 128B line

struct Params {
    const float *x, *edge1, *edge2, *W1, *b1, *iw, *ib;
    const float *e1w, *e1b, *e2w, *e2b;
    const float *n1w, *n1b, *n2w, *n2b;
    const float *m1w, *m1b, *m2w, *m2b, *m3w, *m3b;
    const float *hgw, *hgb;
    const int *hn, *he;
    float4 *xfeat2, *upd2;
    float *a2, *c2, *efeat;
    int *eh;
    int *bar0, *bar1, *mir0, *mir1;
    float4 *out;
};

__device__ __forceinline__ float eluf(float x) { return x > 0.f ? x : __expf(x) - 1.f; }
__device__ __forceinline__ float sigf(float x) { return 1.f / (1.f + __expf(-x)); }
__device__ __forceinline__ float wred(float v) {
#pragma unroll
    for (int o = 32; o > 0; o >>= 1) v += __shfl_down(v, o, 64);
    return v;
}
__device__ __forceinline__ float maskf(float e, float coef) { return (e == 0.f) ? coef : e; }

// Device-wide barrier, r5/r8 lessons combined:
//  - arrivals striped over 64 lines (<=19 serialized RMWs each)
//  - master detects via RELAXED scans with short sleep
//  - release fan-out to 8 mirror lines; pollers read their mirror RELAXED
//    with s_sleep(32) (~0.85us) -> no acquire-inv storm, no fabric queue blowup
//  - exactly ONE full fence per block after detection
// Bounded loops: worst case ~0.4s then wrong answer (absmax fail), never a hang.
__device__ void gbar(int* stripes, int* mirrors, int blk, int tid) {
    __syncthreads();
    if (tid == 0) {
        __threadfence();  // release this block's phase writes
        atomicAdd(&stripes[(blk & (NSTR - 1)) * STRI], 1);
        if (blk == 0) {
            for (int it = 0; it < (1 << 18); ++it) {
                int s = 0;
#pragma unroll
                for (int k = 0; k < NSTR; ++k)
                    s += __hip_atomic_load(&stripes[k * STRI], __ATOMIC_RELAXED,
                                           __HIP_MEMORY_SCOPE_AGENT);
                if (s >= NBLK) break;
                __builtin_amdgcn_s_sleep(2);
            }
#pragma unroll
            for (int k = 0; k < NMIR; ++k)
                __hip_atomic_store(&mirrors[k * STRI], 1, __ATOMIC_RELAXED,
                                   __HIP_MEMORY_SCOPE_AGENT);
        } else {
            int* mf = &mirrors[(blk & (NMIR - 1)) * STRI];
            for (int it = 0; it < (1 << 19); ++it) {
                if (__hip_atomic_load(mf, __ATOMIC_RELAXED, __HIP_MEMORY_SCOPE_AGENT)) break;
                __builtin_amdgcn_s_sleep(32);
            }
        }
        __threadfence();  // acquire: invalidate stale L1/L2 before reading others' writes
    }
    __syncthreads();
}

// Phase 1 (blocks 0..599): fused infer + round1, 2 genes per block (i, i+600).
__device__ void phase1(const Params& p, int blk, int tid) {
    const int lane = tid & 63;
    const int w = tid >> 6;  // batch
    const int i0 = blk, i1 = blk + 600;

    float hi0[4], hi1[4];
    {
        const float* xp0 = p.x + ((size_t)w * G + i0) * NIN;
        const float* xp1 = p.x + ((size_t)w * G + i1) * NIN;
#pragma unroll
        for (int f = 0; f < 4; ++f) {
            float s0 = p.ib[f], s1 = p.ib[f];
#pragma unroll
            for (int k = 0; k < NIN; ++k) {
                s0 += p.iw[f * NIN + k] * xp0[k];
                s1 += p.iw[f * NIN + k] * xp1[k];
            }
            hi0[f] = eluf(s0);
            hi1[f] = eluf(s1);
        }
    }
    const float cb0 = p.e1w[4] * hi0[0] + p.e1w[5] * hi0[1] + p.e1w[6] * hi0[2] + p.e1w[7] * hi0[3] + p.e1b[0];
    const float cb1 = p.e1w[4] * hi1[0] + p.e1w[5] * hi1[1] + p.e1w[6] * hi1[2] + p.e1w[7] * hi1[3] + p.e1b[0];

    const float4* r0 = (const float4*)(p.edge1 + (size_t)i0 * G);
    const float4* r1 = (const float4*)(p.edge1 + (size_t)i1 * G);

    float acc[10];
#pragma unroll
    for (int k = 0; k < 10; ++k) acc[k] = 0.f;

    for (int m = lane; m < 300; m += 64) {
        float e0a[4], e1a[4];
        *(float4*)e0a = r0[m];
        *(float4*)e1a = r1[m];
        float xf[40];
        const float* xp = p.x + ((size_t)w * G + 4 * m) * NIN;
#pragma unroll
        for (int q = 0; q < 10; ++q) *(float4*)&xf[4 * q] = ((const float4*)xp)[q];
#pragma unroll
        for (int s = 0; s < 4; ++s) {
            float h[4];
#pragma unroll
            for (int f = 0; f < 4; ++f) {
                float sv = p.ib[f];
#pragma unroll
                for (int k = 0; k < NIN; ++k) sv += p.iw[f * NIN + k] * xf[10 * s + k];
                h[f] = eluf(sv);
            }
            float aj = p.e1w[0] * h[0] + p.e1w[1] * h[1] + p.e1w[2] * h[2] + p.e1w[3] * h[3];
            float sg0 = sigf(aj + cb0) * maskf(e0a[s], ALPHA);
            float sg1 = sigf(aj + cb1) * maskf(e1a[s], ALPHA);
            acc[0] += sg0 * h[0]; acc[1] += sg0 * h[1]; acc[2] += sg0 * h[2];
            acc[3] += sg0 * h[3]; acc[4] += sg0;
            acc[5] += sg1 * h[0]; acc[6] += sg1 * h[1]; acc[7] += sg1 * h[2];
            acc[8] += sg1 * h[3]; acc[9] += sg1;
        }
    }
#pragma unroll
    for (int k = 0; k < 10; ++k) acc[k] = wred(acc[k]);

    __shared__ float t[2][4][5];
    __shared__ float him[2][4][4];
    __shared__ float hvs[2][4][4];
    __shared__ float stats[2][2];

    if (lane == 0) {
#pragma unroll
        for (int k = 0; k < 5; ++k) { t[0][w][k] = acc[k]; t[1][w][k] = acc[5 + k]; }
#pragma unroll
        for (int f = 0; f < 4; ++f) { him[0][w][f] = hi0[f]; him[1][w][f] = hi1[f]; }
    }
    __syncthreads();

    if (tid < 8) {
        const int b = tid & 3, g = tid >> 2;
        const int i = (g == 0) ? i0 : i1;
        float xi[4] = {him[g][b][0], him[g][b][1], him[g][b][2], him[g][b][3]};
        float ssum = t[g][b][4];
        float r8[8];
#pragma unroll
        for (int k = 0; k < 4; ++k) { r8[k] = t[g][b][k]; r8[4 + k] = xi[k] * ssum; }
        float r[4];
#pragma unroll
        for (int f = 0; f < 4; ++f) {
            float sv = p.n1b[f];
#pragma unroll
            for (int k = 0; k < 8; ++k) sv += p.n1w[f * 8 + k] * r8[k];
            r[f] = eluf(sv);
        }
        const float w1d = p.W1[(size_t)i * G + i], b1i = p.b1[i];
#pragma unroll
        for (int f = 0; f < 4; ++f) {
            float sv = p.m1b[f];
#pragma unroll
            for (int k = 0; k < 4; ++k) sv += p.m1w[f * 8 + k] * r[k] + p.m1w[f * 8 + 4 + k] * xi[k];
            hvs[g][b][f] = eluf(eluf(sv) * w1d + b1i);
        }
    }
    __syncthreads();

    if (tid < 2) {  // BN per gene over (batch, feat) = 16 values
        const int g = tid;
        float mean = 0.f;
#pragma unroll
        for (int bb = 0; bb < 4; ++bb)
#pragma unroll
            for (int f = 0; f < 4; ++f) mean += hvs[g][bb][f];
        mean *= (1.f / 16.f);
        float var = 0.f;
#pragma unroll
        for (int bb = 0; bb < 4; ++bb)
#pragma unroll
            for (int f = 0; f < 4; ++f) { float d = hvs[g][bb][f] - mean; var += d * d; }
        var *= (1.f / 16.f);
        stats[g][0] = mean;
        stats[g][1] = rsqrtf(var + BN_EPS);
    }
    __syncthreads();

    if (tid < 8) {
        const int b = tid & 3, g = tid >> 2;
        const int i = (g == 0) ? i0 : i1;
        const float mean = stats[g][0], sc = stats[g][1];
        float hv[4];
#pragma unroll
        for (int f = 0; f < 4; ++f) hv[f] = (hvs[g][b][f] - mean) * sc;
        p.xfeat2[b * G + i] = make_float4(hv[0], hv[1], hv[2], hv[3]);
        p.a2[b * G + i] = p.e2w[0] * hv[0] + p.e2w[1] * hv[1] + p.e2w[2] * hv[2] + p.e2w[3] * hv[3];
        p.c2[b * G + i] = p.e2w[4] * hv[0] + p.e2w[5] * hv[1] + p.e2w[6] * hv[2] + p.e2w[7] * hv[3] + p.e2b[0];
    }
}

// Phase 2 (all 1200 blocks, gene i = blk): round2 -> upd2; scatter bs into global efeat/eh.
__device__ void phase2(const Params& p, int blk, int tid) {
    const int i = blk;
    const int lane = tid & 63;
    const int w = tid >> 6;

    const float cb = p.c2[w * G + i];
    const float4* erow4 = (const float4*)(p.edge2 + (size_t)i * G);
    const float4* a4 = (const float4*)(p.a2 + (size_t)w * G);

    float acc0 = 0.f, acc1 = 0.f, acc2 = 0.f, acc3 = 0.f, acc4 = 0.f;
    for (int m = lane; m < 300; m += 64) {
        float ea[4], aa[4];
        *(float4*)ea = erow4[m];
        *(float4*)aa = a4[m];
#pragma unroll
        for (int s = 0; s < 4; ++s) {
            float4 xv = p.xfeat2[w * G + 4 * m + s];
            float sg = sigf(aa[s] + cb) * maskf(ea[s], BETA);
            acc0 += sg * xv.x;
            acc1 += sg * xv.y;
            acc2 += sg * xv.z;
            acc3 += sg * xv.w;
            acc4 += sg;
        }
    }
    acc0 = wred(acc0); acc1 = wred(acc1); acc2 = wred(acc2); acc3 = wred(acc3); acc4 = wred(acc4);

    __shared__ float t[4][5];
    __shared__ float hvs[4][4];
    __shared__ float stats[2];
    __shared__ float bsf[4];
    if (lane == 0) { t[w][0] = acc0; t[w][1] = acc1; t[w][2] = acc2; t[w][3] = acc3; t[w][4] = acc4; }
    __syncthreads();

    if (tid < 4) {
        const int b = tid;
        float4 xi4 = p.xfeat2[b * G + i];
        float xi[4] = {xi4.x, xi4.y, xi4.z, xi4.w};
        float ssum = t[b][4];
        float r8[8];
#pragma unroll
        for (int k = 0; k < 4; ++k) { r8[k] = t[b][k]; r8[4 + k] = xi[k] * ssum; }
        float r[4];
#pragma unroll
        for (int f = 0; f < 4; ++f) {
            float sv = p.n2b[f];
#pragma unroll
            for (int k = 0; k < 8; ++k) sv += p.n2w[f * 8 + k] * r8[k];
            r[f] = eluf(sv);
        }
#pragma unroll
        for (int f = 0; f < 4; ++f) {
            float sv = p.m2b[f];
#pragma unroll
            for (int k = 0; k < 4; ++k) sv += p.m2w[f * 8 + k] * r[k] + p.m2w[f * 8 + 4 + k] * xi[k];
            hvs[b][f] = eluf(sv);
        }
    }
    __syncthreads();

    if (tid == 0) {
        float mean = 0.f;
#pragma unroll
        for (int bb = 0; bb < 4; ++bb)
#pragma unroll
            for (int f = 0; f < 4; ++f) mean += hvs[bb][f];
        mean *= (1.f / 16.f);
        float var = 0.f;
#pragma unroll
        for (int bb = 0; bb < 4; ++bb)
#pragma unroll
            for (int f = 0; f < 4; ++f) { float d = hvs[bb][f] - mean; var += d * d; }
        var *= (1.f / 16.f);
        stats[0] = mean;
        stats[1] = rsqrtf(var + BN_EPS);
    }
    __syncthreads();

    if (tid < 4) {
        const int b = tid;
        const float mean = stats[0], sc = stats[1];
        float hv[4];
#pragma unroll
        for (int f = 0; f < 4; ++f) hv[f] = (hvs[b][f] - mean) * sc;
        p.upd2[b * G + i] = make_float4(hv[0], hv[1], hv[2], hv[3]);
        hvs[b][0] = hv[0]; hvs[b][1] = hv[1]; hvs[b][2] = hv[2]; hvs[b][3] = hv[3];
    }
    __syncthreads();

    if (tid < 4) {
        const int f = tid;
        float sv = 0.f;
#pragma unroll
        for (int bb = 0; bb < 4; ++bb)
#pragma unroll
            for (int k = 0; k < 4; ++k) sv += p.hgw[f * 4 + k] * hvs[bb][k];
        bsf[f] = sv;
    }
    __syncthreads();

    const float v0 = bsf[0], v1 = bsf[1], v2 = bsf[2], v3 = bsf[3];
    for (int cI = tid; cI < NINC; cI += 256) {
        if (p.hn[cI] == i) {
            int e = p.he[cI];
            atomicAdd(&p.eh[e], 1);
            atomicAdd(&p.efeat[e * 4 + 0], v0);
            atomicAdd(&p.efeat[e * 4 + 1], v1);
            atomicAdd(&p.efeat[e * 4 + 2], v2);
            atomicAdd(&p.efeat[e * 4 + 3], v3);
        }
    }
}

// Phase 3 (all 1200 blocks, gene i = blk): gather hx[i] + final MLP (x4 batches).
__device__ void phase3(const Params& p, int blk, int tid) {
    const int i = blk;
    const int lane = tid & 63;
    const int w = tid >> 6;

    float a0 = 0.f, a1 = 0.f, a2v = 0.f, a3 = 0.f, cf = 0.f;
    for (int cI = tid; cI < NINC; cI += 256) {
        if (p.hn[cI] == i) {
            int e = p.he[cI];
            float binv = 0.25f / (float)p.eh[e];  // bdeg = BSZ * hist(edges)
            a0 += p.efeat[e * 4 + 0] * binv;
            a1 += p.efeat[e * 4 + 1] * binv;
            a2v += p.efeat[e * 4 + 2] * binv;
            a3 += p.efeat[e * 4 + 3] * binv;
            cf += 1.f;
        }
    }
    a0 = wred(a0); a1 = wred(a1); a2v = wred(a2v); a3 = wred(a3); cf = wred(cf);
    __shared__ float red[4][5];
    if (lane == 0) { red[w][0] = a0; red[w][1] = a1; red[w][2] = a2v; red[w][3] = a3; red[w][4] = cf; }
    __syncthreads();

    if (tid < 4) {
        const int b = tid;
        float dg = red[0][4] + red[1][4] + red[2][4] + red[3][4];
        float dinv = dg > 0.f ? 1.f / dg : 0.f;
        float hxp[4];
#pragma unroll
        for (int f = 0; f < 4; ++f) {
            float hx = (red[0][f] + red[1][f] + red[2][f] + red[3][f]) * dinv;
            hxp[f] = eluf(hx + p.hgb[f]);
        }
        float4 u4 = p.upd2[b * G + i];
        float u[4] = {u4.x, u4.y, u4.z, u4.w};
        float o4[4];
#pragma unroll
        for (int f = 0; f < 4; ++f) {
            float sv = p.m3b[f];
#pragma unroll
            for (int k = 0; k < 4; ++k)
                sv += p.m3w[f * 8 + k] * u[k] + p.m3w[f * 8 + 4 + k] * hxp[k];
            o4[f] = eluf(sv);
        }
        p.out[b * G + i] = make_float4(o4[0], o4[1], o4[2], o4[3]);
    }
}

__global__ __launch_bounds__(256, 8)  // VGPR<=64 -> capacity 2048 blocks >> 1200: co-residency certain
void mega_kernel(Params p) {
    const int blk = blockIdx.x, tid = threadIdx.x;
    if (blk < 600) phase1(p, blk, tid);
    gbar(p.bar0, p.mir0, blk, tid);
    phase2(p, blk, tid);
    gbar(p.bar1, p.mir1, blk, tid);
    phase3(p, blk, tid);
}

extern "C" void kernel_launch(void* const* d_in, const int* in_sizes, int n_in,
                              void* d_out, int out_size, void* d_ws, size_t ws_size,
                              hipStream_t stream) {
    Params p;
    p.x     = (const float*)d_in[0];
    p.edge1 = (const float*)d_in[1];
    p.edge2 = (const float*)d_in[2];
    p.W1    = (const float*)d_in[3];
    p.b1    = (const float*)d_in[4];
    p.iw    = (const float*)d_in[5];
    p.ib    = (const float*)d_in[6];
    p.e1w   = (const float*)d_in[7];
    p.e1b   = (const float*)d_in[8];
    p.e2w   = (const float*)d_in[9];
    p.e2b   = (const float*)d_in[10];
    p.n1w   = (const float*)d_in[11];
    p.n1b   = (const float*)d_in[12];
    p.n2w   = (const float*)d_in[13];
    p.n2b   = (const float*)d_in[14];
    p.m1w   = (const float*)d_in[15];
    p.m1b   = (const float*)d_in[16];
    p.m2w   = (const float*)d_in[17];
    p.m2b   = (const float*)d_in[18];
    p.m3w   = (const float*)d_in[19];
    p.m3b   = (const float*)d_in[20];
    p.hgw   = (const float*)d_in[21];
    p.hgb   = (const float*)d_in[22];
    p.hn    = (const int*)d_in[23];
    p.he    = (const int*)d_in[24];

    char* ws = (char*)d_ws;
    p.xfeat2 = (float4*)(ws + 0);        // 76800
    p.upd2   = (float4*)(ws + 76800);    // 76800
    p.a2     = (float*)(ws + 153600);    // 19200
    p.c2     = (float*)(ws + 172800);    // 19200
    // ---- memset-covered region (24 KB) ----
    char* z  = ws + 192000;
    p.efeat  = (float*)(z + 0);          // 4800
    p.eh     = (int*)(z + 4800);         // 1200 (ends 6000)
    p.bar0   = (int*)(z + 6144);         // 64*128 = 8192
    p.bar1   = (int*)(z + 14336);        // 8192
    p.mir0   = (int*)(z + 22528);        // 8*128 = 1024
    p.mir1   = (int*)(z + 23552);        // 1024 (ends 24576)
    p.out    = (float4*)d_out;

    hipMemsetAsync(z, 0, 24576, stream);
    mega_kernel<<<NBLK, 256, 0, stream>>>(p);
}

// Round 10
// 151.642 us; speedup vs baseline: 3.8410x; 1.0015x over previous
//
#include <hip/hip_runtime.h>
#include <math.h>

#define G 1200
#define NIN 10
#define NHE 300
#define NINC 4800
#define ALPHA 0.005f
#define BETA 5e-5f
#define BN_EPS 1e-5f
#define NBLK 1200
#define NSTR 64   // arrival stripes (128B apart)
#define NMIR 8    // release mirror flags (128B apart)
#define STRI 32   // ints per 128B line

struct Params {
    const float *x, *edge1, *edge2, *W1, *b1, *iw, *ib;
    const float *e1w, *e1b, *e2w, *e2b;
    const float *n1w, *n1b, *n2w, *n2b;
    const float *m1w, *m1b, *m2w, *m2b, *m3w, *m3b;
    const float *hgw, *hgb;
    const int *hn, *he;
    float4 *xfeat2, *upd2;
    float *a2, *c2, *efeat;
    int *eh;
    int *bar0, *bar1, *mir0, *mir1;
    float4 *out;
};

__device__ __forceinline__ float eluf(float x) { return x > 0.f ? x : __expf(x) - 1.f; }
__device__ __forceinline__ float sigf(float x) { return 1.f / (1.f + __expf(-x)); }
__device__ __forceinline__ float wred(float v) {
#pragma unroll
    for (int o = 32; o > 0; o >>= 1) v += __shfl_down(v, o, 64);
    return v;
}
__device__ __forceinline__ float maskf(float e, float coef) { return (e == 0.f) ? coef : e; }

// Device-wide barrier, r5/r8 lessons combined:
//  - arrivals striped over 64 lines (<=19 serialized RMWs each)
//  - master detects via RELAXED scans with short sleep
//  - release fan-out to 8 mirror lines; pollers read their mirror RELAXED
//    with s_sleep(32) (~0.85us) -> no acquire-inv storm, no fabric queue blowup
//  - exactly ONE full fence per block after detection
// Bounded loops: worst case ~0.4s then wrong answer (absmax fail), never a hang.
__device__ void gbar(int* stripes, int* mirrors, int blk, int tid) {
    __syncthreads();
    if (tid == 0) {
        __threadfence();  // release this block's phase writes
        atomicAdd(&stripes[(blk & (NSTR - 1)) * STRI], 1);
        if (blk == 0) {
            for (int it = 0; it < (1 << 18); ++it) {
                int s = 0;
#pragma unroll
                for (int k = 0; k < NSTR; ++k)
                    s += __hip_atomic_load(&stripes[k * STRI], __ATOMIC_RELAXED,
                                           __HIP_MEMORY_SCOPE_AGENT);
                if (s >= NBLK) break;
                __builtin_amdgcn_s_sleep(2);
            }
#pragma unroll
            for (int k = 0; k < NMIR; ++k)
                __hip_atomic_store(&mirrors[k * STRI], 1, __ATOMIC_RELAXED,
                                   __HIP_MEMORY_SCOPE_AGENT);
        } else {
            int* mf = &mirrors[(blk & (NMIR - 1)) * STRI];
            for (int it = 0; it < (1 << 19); ++it) {
                if (__hip_atomic_load(mf, __ATOMIC_RELAXED, __HIP_MEMORY_SCOPE_AGENT)) break;
                __builtin_amdgcn_s_sleep(32);
            }
        }
        __threadfence();  // acquire: invalidate stale L1/L2 before reading others' writes
    }
    __syncthreads();
}

// Phase 1 (blocks 0..599): fused infer + round1, 2 genes per block (i, i+600).
__device__ void phase1(const Params& p, int blk, int tid) {
    const int lane = tid & 63;
    const int w = tid >> 6;  // batch
    const int i0 = blk, i1 = blk + 600;

    float hi0[4], hi1[4];
    {
        const float* xp0 = p.x + ((size_t)w * G + i0) * NIN;
        const float* xp1 = p.x + ((size_t)w * G + i1) * NIN;
#pragma unroll
        for (int f = 0; f < 4; ++f) {
            float s0 = p.ib[f], s1 = p.ib[f];
#pragma unroll
            for (int k = 0; k < NIN; ++k) {
                s0 += p.iw[f * NIN + k] * xp0[k];
                s1 += p.iw[f * NIN + k] * xp1[k];
            }
            hi0[f] = eluf(s0);
            hi1[f] = eluf(s1);
        }
    }
    const float cb0 = p.e1w[4] * hi0[0] + p.e1w[5] * hi0[1] + p.e1w[6] * hi0[2] + p.e1w[7] * hi0[3] + p.e1b[0];
    const float cb1 = p.e1w[4] * hi1[0] + p.e1w[5] * hi1[1] + p.e1w[6] * hi1[2] + p.e1w[7] * hi1[3] + p.e1b[0];

    const float4* r0 = (const float4*)(p.edge1 + (size_t)i0 * G);
    const float4* r1 = (const float4*)(p.edge1 + (size_t)i1 * G);

    float acc[10];
#pragma unroll
    for (int k = 0; k < 10; ++k) acc[k] = 0.f;

    for (int m = lane; m < 300; m += 64) {
        float e0a[4], e1a[4];
        *(float4*)e0a = r0[m];
        *(float4*)e1a = r1[m];
        float xf[40];
        const float* xp = p.x + ((size_t)w * G + 4 * m) * NIN;
#pragma unroll
        for (int q = 0; q < 10; ++q) *(float4*)&xf[4 * q] = ((const float4*)xp)[q];
#pragma unroll
        for (int s = 0; s < 4; ++s) {
            float h[4];
#pragma unroll
            for (int f = 0; f < 4; ++f) {
                float sv = p.ib[f];
#pragma unroll
                for (int k = 0; k < NIN; ++k) sv += p.iw[f * NIN + k] * xf[10 * s + k];
                h[f] = eluf(sv);
            }
            float aj = p.e1w[0] * h[0] + p.e1w[1] * h[1] + p.e1w[2] * h[2] + p.e1w[3] * h[3];
            float sg0 = sigf(aj + cb0) * maskf(e0a[s], ALPHA);
            float sg1 = sigf(aj + cb1) * maskf(e1a[s], ALPHA);
            acc[0] += sg0 * h[0]; acc[1] += sg0 * h[1]; acc[2] += sg0 * h[2];
            acc[3] += sg0 * h[3]; acc[4] += sg0;
            acc[5] += sg1 * h[0]; acc[6] += sg1 * h[1]; acc[7] += sg1 * h[2];
            acc[8] += sg1 * h[3]; acc[9] += sg1;
        }
    }
#pragma unroll
    for (int k = 0; k < 10; ++k) acc[k] = wred(acc[k]);

    __shared__ float t[2][4][5];
    __shared__ float him[2][4][4];
    __shared__ float hvs[2][4][4];
    __shared__ float stats[2][2];

    if (lane == 0) {
#pragma unroll
        for (int k = 0; k < 5; ++k) { t[0][w][k] = acc[k]; t[1][w][k] = acc[5 + k]; }
#pragma unroll
        for (int f = 0; f < 4; ++f) { him[0][w][f] = hi0[f]; him[1][w][f] = hi1[f]; }
    }
    __syncthreads();

    if (tid < 8) {
        const int b = tid & 3, g = tid >> 2;
        const int i = (g == 0) ? i0 : i1;
        float xi[4] = {him[g][b][0], him[g][b][1], him[g][b][2], him[g][b][3]};
        float ssum = t[g][b][4];
        float r8[8];
#pragma unroll
        for (int k = 0; k < 4; ++k) { r8[k] = t[g][b][k]; r8[4 + k] = xi[k] * ssum; }
        float r[4];
#pragma unroll
        for (int f = 0; f < 4; ++f) {
            float sv = p.n1b[f];
#pragma unroll
            for (int k = 0; k < 8; ++k) sv += p.n1w[f * 8 + k] * r8[k];
            r[f] = eluf(sv);
        }
        const float w1d = p.W1[(size_t)i * G + i], b1i = p.b1[i];
#pragma unroll
        for (int f = 0; f < 4; ++f) {
            float sv = p.m1b[f];
#pragma unroll
            for (int k = 0; k < 4; ++k) sv += p.m1w[f * 8 + k] * r[k] + p.m1w[f * 8 + 4 + k] * xi[k];
            hvs[g][b][f] = eluf(eluf(sv) * w1d + b1i);
        }
    }
    __syncthreads();

    if (tid < 2) {  // BN per gene over (batch, feat) = 16 values
        const int g = tid;
        float mean = 0.f;
#pragma unroll
        for (int bb = 0; bb < 4; ++bb)
#pragma unroll
            for (int f = 0; f < 4; ++f) mean += hvs[g][bb][f];
        mean *= (1.f / 16.f);
        float var = 0.f;
#pragma unroll
        for (int bb = 0; bb < 4; ++bb)
#pragma unroll
            for (int f = 0; f < 4; ++f) { float d = hvs[g][bb][f] - mean; var += d * d; }
        var *= (1.f / 16.f);
        stats[g][0] = mean;
        stats[g][1] = rsqrtf(var + BN_EPS);
    }
    __syncthreads();

    if (tid < 8) {
        const int b = tid & 3, g = tid >> 2;
        const int i = (g == 0) ? i0 : i1;
        const float mean = stats[g][0], sc = stats[g][1];
        float hv[4];
#pragma unroll
        for (int f = 0; f < 4; ++f) hv[f] = (hvs[g][b][f] - mean) * sc;
        p.xfeat2[b * G + i] = make_float4(hv[0], hv[1], hv[2], hv[3]);
        p.a2[b * G + i] = p.e2w[0] * hv[0] + p.e2w[1] * hv[1] + p.e2w[2] * hv[2] + p.e2w[3] * hv[3];
        p.c2[b * G + i] = p.e2w[4] * hv[0] + p.e2w[5] * hv[1] + p.e2w[6] * hv[2] + p.e2w[7] * hv[3] + p.e2b[0];
    }
}

// Phase 2 (all 1200 blocks, gene i = blk): round2 -> upd2; scatter bs into global efeat/eh.
__device__ void phase2(const Params& p, int blk, int tid) {
    const int i = blk;
    const int lane = tid & 63;
    const int w = tid >> 6;

    const float cb = p.c2[w * G + i];
    const float4* erow4 = (const float4*)(p.edge2 + (size_t)i * G);
    const float4* a4 = (const float4*)(p.a2 + (size_t)w * G);

    float acc0 = 0.f, acc1 = 0.f, acc2 = 0.f, acc3 = 0.f, acc4 = 0.f;
    for (int m = lane; m < 300; m += 64) {
        float ea[4], aa[4];
        *(float4*)ea = erow4[m];
        *(float4*)aa = a4[m];
#pragma unroll
        for (int s = 0; s < 4; ++s) {
            float4 xv = p.xfeat2[w * G + 4 * m + s];
            float sg = sigf(aa[s] + cb) * maskf(ea[s], BETA);
            acc0 += sg * xv.x;
            acc1 += sg * xv.y;
            acc2 += sg * xv.z;
            acc3 += sg * xv.w;
            acc4 += sg;
        }
    }
    acc0 = wred(acc0); acc1 = wred(acc1); acc2 = wred(acc2); acc3 = wred(acc3); acc4 = wred(acc4);

    __shared__ float t[4][5];
    __shared__ float hvs[4][4];
    __shared__ float stats[2];
    __shared__ float bsf[4];
    if (lane == 0) { t[w][0] = acc0; t[w][1] = acc1; t[w][2] = acc2; t[w][3] = acc3; t[w][4] = acc4; }
    __syncthreads();

    if (tid < 4) {
        const int b = tid;
        float4 xi4 = p.xfeat2[b * G + i];
        float xi[4] = {xi4.x, xi4.y, xi4.z, xi4.w};
        float ssum = t[b][4];
        float r8[8];
#pragma unroll
        for (int k = 0; k < 4; ++k) { r8[k] = t[b][k]; r8[4 + k] = xi[k] * ssum; }
        float r[4];
#pragma unroll
        for (int f = 0; f < 4; ++f) {
            float sv = p.n2b[f];
#pragma unroll
            for (int k = 0; k < 8; ++k) sv += p.n2w[f * 8 + k] * r8[k];
            r[f] = eluf(sv);
        }
#pragma unroll
        for (int f = 0; f < 4; ++f) {
            float sv = p.m2b[f];
#pragma unroll
            for (int k = 0; k < 4; ++k) sv += p.m2w[f * 8 + k] * r[k] + p.m2w[f * 8 + 4 + k] * xi[k];
            hvs[b][f] = eluf(sv);
        }
    }
    __syncthreads();

    if (tid == 0) {
        float mean = 0.f;
#pragma unroll
        for (int bb = 0; bb < 4; ++bb)
#pragma unroll
            for (int f = 0; f < 4; ++f) mean += hvs[bb][f];
        mean *= (1.f / 16.f);
        float var = 0.f;
#pragma unroll
        for (int bb = 0; bb < 4; ++bb)
#pragma unroll
            for (int f = 0; f < 4; ++f) { float d = hvs[bb][f] - mean; var += d * d; }
        var *= (1.f / 16.f);
        stats[0] = mean;
        stats[1] = rsqrtf(var + BN_EPS);
    }
    __syncthreads();

    if (tid < 4) {
        const int b = tid;
        const float mean = stats[0], sc = stats[1];
        float hv[4];
#pragma unroll
        for (int f = 0; f < 4; ++f) hv[f] = (hvs[b][f] - mean) * sc;
        p.upd2[b * G + i] = make_float4(hv[0], hv[1], hv[2], hv[3]);
        hvs[b][0] = hv[0]; hvs[b][1] = hv[1]; hvs[b][2] = hv[2]; hvs[b][3] = hv[3];
    }
    __syncthreads();

    if (tid < 4) {
        const int f = tid;
        float sv = 0.f;
#pragma unroll
        for (int bb = 0; bb < 4; ++bb)
#pragma unroll
            for (int k = 0; k < 4; ++k) sv += p.hgw[f * 4 + k] * hvs[bb][k];
        bsf[f] = sv;
    }
    __syncthreads();

    const float v0 = bsf[0], v1 = bsf[1], v2 = bsf[2], v3 = bsf[3];
    for (int cI = tid; cI < NINC; cI += 256) {
        if (p.hn[cI] == i) {
            int e = p.he[cI];
            atomicAdd(&p.eh[e], 1);
            atomicAdd(&p.efeat[e * 4 + 0], v0);
            atomicAdd(&p.efeat[e * 4 + 1], v1);
            atomicAdd(&p.efeat[e * 4 + 2], v2);
            atomicAdd(&p.efeat[e * 4 + 3], v3);
        }
    }
}

// Phase 3 (all 1200 blocks, gene i = blk): gather hx[i] + final MLP (x4 batches).
__device__ void phase3(const Params& p, int blk, int tid) {
    const int i = blk;
    const int lane = tid & 63;
    const int w = tid >> 6;

    float a0 = 0.f, a1 = 0.f, a2v = 0.f, a3 = 0.f, cf = 0.f;
    for (int cI = tid; cI < NINC; cI += 256) {
        if (p.hn[cI] == i) {
            int e = p.he[cI];
            float binv = 0.25f / (float)p.eh[e];  // bdeg = BSZ * hist(edges)
            a0 += p.efeat[e * 4 + 0] * binv;
            a1 += p.efeat[e * 4 + 1] * binv;
            a2v += p.efeat[e * 4 + 2] * binv;
            a3 += p.efeat[e * 4 + 3] * binv;
            cf += 1.f;
        }
    }
    a0 = wred(a0); a1 = wred(a1); a2v = wred(a2v); a3 = wred(a3); cf = wred(cf);
    __shared__ float red[4][5];
    if (lane == 0) { red[w][0] = a0; red[w][1] = a1; red[w][2] = a2v; red[w][3] = a3; red[w][4] = cf; }
    __syncthreads();

    if (tid < 4) {
        const int b = tid;
        float dg = red[0][4] + red[1][4] + red[2][4] + red[3][4];
        float dinv = dg > 0.f ? 1.f / dg : 0.f;
        float hxp[4];
#pragma unroll
        for (int f = 0; f < 4; ++f) {
            float hx = (red[0][f] + red[1][f] + red[2][f] + red[3][f]) * dinv;
            hxp[f] = eluf(hx + p.hgb[f]);
        }
        float4 u4 = p.upd2[b * G + i];
        float u[4] = {u4.x, u4.y, u4.z, u4.w};
        float o4[4];
#pragma unroll
        for (int f = 0; f < 4; ++f) {
            float sv = p.m3b[f];
#pragma unroll
            for (int k = 0; k < 4; ++k)
                sv += p.m3w[f * 8 + k] * u[k] + p.m3w[f * 8 + 4 + k] * hxp[k];
            o4[f] = eluf(sv);
        }
        p.out[b * G + i] = make_float4(o4[0], o4[1], o4[2], o4[3]);
    }
}

__global__ __launch_bounds__(256, 8)  // VGPR<=64 -> capacity 2048 blocks >> 1200: co-residency certain
void mega_kernel(Params p) {
    const int blk = blockIdx.x, tid = threadIdx.x;
    if (blk < 600) phase1(p, blk, tid);
    gbar(p.bar0, p.mir0, blk, tid);
    phase2(p, blk, tid);
    gbar(p.bar1, p.mir1, blk, tid);
    phase3(p, blk, tid);
}

extern "C" void kernel_launch(void* const* d_in, const int* in_sizes, int n_in,
                              void* d_out, int out_size, void* d_ws, size_t ws_size,
                              hipStream_t stream) {
    Params p;
    p.x     = (const float*)d_in[0];
    p.edge1 = (const float*)d_in[1];
    p.edge2 = (const float*)d_in[2];
    p.W1    = (const float*)d_in[3];
    p.b1    = (const float*)d_in[4];
    p.iw    = (const float*)d_in[5];
    p.ib    = (const float*)d_in[6];
    p.e1w   = (const float*)d_in[7];
    p.e1b   = (const float*)d_in[8];
    p.e2w   = (const float*)d_in[9];
    p.e2b   = (const float*)d_in[10];
    p.n1w   = (const float*)d_in[11];
    p.n1b   = (const float*)d_in[12];
    p.n2w   = (const float*)d_in[13];
    p.n2b   = (const float*)d_in[14];
    p.m1w   = (const float*)d_in[15];
    p.m1b   = (const float*)d_in[16];
    p.m2w   = (const float*)d_in[17];
    p.m2b   = (const float*)d_in[18];
    p.m3w   = (const float*)d_in[19];
    p.m3b   = (const float*)d_in[20];
    p.hgw   = (const float*)d_in[21];
    p.hgb   = (const float*)d_in[22];
    p.hn    = (const int*)d_in[23];
    p.he    = (const int*)d_in[24];

    char* ws = (char*)d_ws;
    p.xfeat2 = (float4*)(ws + 0);        // 76800
    p.upd2   = (float4*)(ws + 76800);    // 76800
    p.a2     = (float*)(ws + 153600);    // 19200
    p.c2     = (float*)(ws + 172800);    // 19200
    // ---- memset-covered region (24 KB) ----
    char* z  = ws + 192000;
    p.efeat  = (float*)(z + 0);          // 4800
    p.eh     = (int*)(z + 4800);         // 1200 (ends 6000)
    p.bar0   = (int*)(z + 6144);         // 64*128 = 8192
    p.bar1   = (int*)(z + 14336);        // 8192
    p.mir0   = (int*)(z + 22528);        // 8*128 = 1024
    p.mir1   = (int*)(z + 23552);        // 1024 (ends 24576)
    p.out    = (float4*)d_out;

    hipMemsetAsync(z, 0, 24576, stream);
    mega_kernel<<<NBLK, 256, 0, stream>>>(p);
}